// Round 5
// baseline (1245.480 us; speedup 1.0000x reference)
//
#include <hip/hip_runtime.h>

// ---------------------------------------------------------------------------
// PaiNN edge message kernel, MI355X (gfx950)
// E=262144, F=128. Split-bf16 (hi/lo) MFMA GEMMs, fp32 elsewhere.
// R4/R5: latency-bound fix — 2 blocks/CU (NBLK=512, launch_bounds(512,4)
// forces VGPR<=128), balanced fc mapping {w, w+8, w+16} so every wave does 12
// v-loads, v-prefetch at tile top, rbf computed pre-sync1 from per-thread r
// (rbf/urA double-buffered; 2 lgkmcnt-only barriers per tile).
// ---------------------------------------------------------------------------

#define E_TOT  262144
#define NTILES 16384     // E / 16
#define NBLK   512       // 2 blocks/CU; 32 tiles per block
#define PART_STRIDE 896  // per-block partials: v1[3][128] v2[3][128] s[128]

typedef __attribute__((ext_vector_type(8))) short bf16x8;
typedef __attribute__((ext_vector_type(4))) float f32x4;
typedef __attribute__((ext_vector_type(4))) unsigned short u16x4;

static __device__ __forceinline__ unsigned short f2bf(float f) {
  union { float f; unsigned u; } x; x.f = f;
  unsigned r = x.u + 0x7fffu + ((x.u >> 16) & 1u);   // RNE
  return (unsigned short)(r >> 16);
}
static __device__ __forceinline__ float bf2f(unsigned short h) {
  union { unsigned u; float f; } x; x.u = ((unsigned)h) << 16;
  return x.f;
}

// lgkmcnt-only barrier (m201 pattern): LDS-correct, global loads stay in
// flight across it (no vmcnt(0) drain).
#define BAR() do {                                           \
    asm volatile("s_waitcnt lgkmcnt(0)" ::: "memory");       \
    __builtin_amdgcn_s_barrier();                            \
    asm volatile("" ::: "memory");                           \
  } while (0)

// --- kernel 1: weights -> bf16 hi/lo pairs, transposed for B-fragments ----
__global__ void prep_kernel(const float* __restrict__ W1, const float* __restrict__ W2,
                            const float* __restrict__ Wr,
                            unsigned short* __restrict__ w1t, unsigned short* __restrict__ w2t,
                            unsigned short* __restrict__ wrt) {
  int idx = blockIdx.x * 256 + threadIdx.x;
  if (idx < 16384) {                       // W1 (128x128) -> W1T[col][k]
    int k = idx >> 7, c = idx & 127;
    float x = W1[idx];
    unsigned short hi = f2bf(x);
    w1t[c * 128 + k] = hi;
    w1t[16384 + c * 128 + k] = f2bf(x - bf2f(hi));
  } else if (idx < 65536) {                // W2 (128x384) -> W2T[col][k]
    int i = idx - 16384;
    int k = i / 384, c = i % 384;
    float x = W2[i];
    unsigned short hi = f2bf(x);
    w2t[c * 128 + k] = hi;
    w2t[49152 + c * 128 + k] = f2bf(x - bf2f(hi));
  } else if (idx < 77824) {                // Wr (20x384) -> WrT[col][n], n padded to 32
    int i = idx - 65536;
    int c = i >> 5, n = i & 31;
    float x = (n < 20) ? Wr[n * 384 + c] : 0.0f;
    unsigned short hi = f2bf(x);
    wrt[c * 32 + n] = hi;
    wrt[12288 + c * 32 + n] = f2bf(x - bf2f(hi));
  }
}

// --- kernel 2: main. 512 threads = 8 waves. Tile = 16 edges. --------------
__global__ __launch_bounds__(512, 4) void painn_main(
    const float* __restrict__ s, const float* __restrict__ r, const float* __restrict__ v,
    const float* __restrict__ b1, const float* __restrict__ b2, const float* __restrict__ br,
    const unsigned short* __restrict__ w1t, const unsigned short* __restrict__ w2t,
    const unsigned short* __restrict__ wrt, float* __restrict__ partials)
{
  __shared__ __align__(16) unsigned short sAh[16][136], sAl[16][136];
  __shared__ __align__(16) unsigned short hAh[16][136], hAl[16][136];
  __shared__ __align__(16) unsigned short rbfh[2][16][40], rbfl[2][16][40];
  __shared__ float4 urA[2][16];   // dbuf: {ux, uy, uz, fcut}

  const int tid = threadIdx.x;
  const int wv  = tid >> 6;
  const int ln  = tid & 63;
  const int l15 = ln & 15;
  const int q4  = ln >> 4;
  const int jcol = wv * 16 + l15;          // per-wave column slot, 0..127

  // zero rbf pad cols 20..31 (read by K=32 MFMA) for both buffers, hi+lo
  for (int i = tid; i < 2 * 16 * 12; i += 512) {
    const int b = i / 192, rw = (i / 12) % 16, cc = 20 + (i % 12);
    rbfh[b][rw][cc] = 0; rbfl[b][rw][cc] = 0;
  }

  // ---- weight fragments (hi/lo); compiler remats what exceeds 128 VGPRs ----
  bf16x8 w1fh[4], w1fl[4];
#pragma unroll
  for (int ks = 0; ks < 4; ++ks) {
    w1fh[ks] = *(const bf16x8*)(w1t + jcol * 128 + ks * 32 + q4 * 8);
    w1fl[ks] = *(const bf16x8*)(w1t + 16384 + jcol * 128 + ks * 32 + q4 * 8);
  }
  const float b1v = b1[jcol];

  float b2v[3], brv[3];
  bf16x8 w2fh[3][4], w2fl[3][4], wrfh[3], wrfl[3];
#pragma unroll
  for (int fci = 0; fci < 3; ++fci) {
    const int j = jcol + fci * 128;        // fc = wv + 8*fci, j = fc*16+l15
    b2v[fci] = b2[j];
    brv[fci] = br[j];
#pragma unroll
    for (int ks = 0; ks < 4; ++ks) {
      w2fh[fci][ks] = *(const bf16x8*)(w2t + j * 128 + ks * 32 + q4 * 8);
      w2fl[fci][ks] = *(const bf16x8*)(w2t + 49152 + j * 128 + ks * 32 + q4 * 8);
    }
    wrfh[fci] = *(const bf16x8*)(wrt + j * 32 + q4 * 8);
    wrfl[fci] = *(const bf16x8*)(wrt + 12288 + j * 32 + q4 * 8);
  }

  float accS = 0.f;
  float accV1[3] = {0.f, 0.f, 0.f};
  float accV2[3] = {0.f, 0.f, 0.f};
  const f32x4 zero4 = {0.f, 0.f, 0.f, 0.f};

  // ---- prefetch s (one float4/thread) + r (threads<320, own edge copy) ----
  const int srow = tid >> 5;               // 0..15
  const int sc4  = (tid & 31) * 4;         // float col 0..124
  float4 pf = *(const float4*)(s + (size_t)((size_t)blockIdx.x * 16 + srow) * 128 + sc4);
  float rx = 0.f, ry = 0.f, rz = 0.f;
  if (tid < 320) {
    const float* rp = r + ((size_t)blockIdx.x * 16 + (tid & 15)) * 3;
    rx = rp[0]; ry = rp[1]; rz = rp[2];
  }

  int p = 0;
  for (int t = blockIdx.x; t < NTILES; t += NBLK, p ^= 1) {
    const int e0 = t * 16;

    // ---- v-prefetch for THIS tile (consumed in epilogue, ~2 phases later)
    float vp[4][3];
    {
      const float* vb = v + (size_t)e0 * 384 + jcol;
#pragma unroll
      for (int rr = 0; rr < 4; ++rr) {
        const int el = q4 * 4 + rr;
#pragma unroll
        for (int c = 0; c < 3; ++c)
          vp[rr][c] = vb[(size_t)el * 384 + c * 128];
      }
    }

    // ---- phase A: stage s tile (hi/lo), geometry + rbf from local r ----
    {
      u16x4 vh, vl;
      unsigned short h0 = f2bf(pf.x); vh[0] = h0; vl[0] = f2bf(pf.x - bf2f(h0));
      unsigned short h1 = f2bf(pf.y); vh[1] = h1; vl[1] = f2bf(pf.y - bf2f(h1));
      unsigned short h2 = f2bf(pf.z); vh[2] = h2; vl[2] = f2bf(pf.z - bf2f(h2));
      unsigned short h3 = f2bf(pf.w); vh[3] = h3; vl[3] = f2bf(pf.w - bf2f(h3));
      *(u16x4*)&sAh[srow][sc4] = vh;
      *(u16x4*)&sAl[srow][sc4] = vl;
    }
    if (tid < 320) {
      const float d = sqrtf(rx * rx + ry * ry + rz * rz);
      const float inv = 1.0f / d;
      const int n = tid >> 4;              // 0..19
      const float val = sinf(0.62831853071795864f * (float)(n + 1) * d) * inv;
      const unsigned short hi = f2bf(val);
      rbfh[p][tid & 15][n] = hi;
      rbfl[p][tid & 15][n] = f2bf(val - bf2f(hi));
      if (tid < 16) {
        const float fcut = (d < 5.0f) ? 0.5f * (cosf(0.62831853071795864f * d) + 1.0f) : 0.0f;
        float4 u4; u4.x = rx * inv; u4.y = ry * inv; u4.z = rz * inv; u4.w = fcut;
        urA[p][tid] = u4;
      }
    }
    BAR();   // sync1: sA visible

    // ---- GEMM1: h_pre = s@W1 (split, 12 MFMA) ----
    f32x4 hacc = zero4;
#pragma unroll
    for (int ks = 0; ks < 4; ++ks) {
      const bf16x8 ah = *(const bf16x8*)&sAh[l15][ks * 32 + q4 * 8];
      const bf16x8 al = *(const bf16x8*)&sAl[l15][ks * 32 + q4 * 8];
      hacc = __builtin_amdgcn_mfma_f32_16x16x32_bf16(ah, w1fh[ks], hacc, 0, 0, 0);
      hacc = __builtin_amdgcn_mfma_f32_16x16x32_bf16(al, w1fh[ks], hacc, 0, 0, 0);
      hacc = __builtin_amdgcn_mfma_f32_16x16x32_bf16(ah, w1fl[ks], hacc, 0, 0, 0);
    }
    // silu fp32, split-store h (D layout: row=q4*4+rr, col=jcol)
#pragma unroll
    for (int rr = 0; rr < 4; ++rr) {
      const float x = hacc[rr] + b1v;
      const float hvv = x / (1.0f + __expf(-x));
      const unsigned short hi = f2bf(hvv);
      hAh[q4 * 4 + rr][jcol] = hi;
      hAl[q4 * 4 + rr][jcol] = f2bf(hvv - bf2f(hi));
    }

    // ---- s/r prefetch for tile t+NBLK (stays in flight across barriers) ----
    {
      int tn = t + NBLK;
      if (tn >= NTILES) tn = blockIdx.x;   // harmless valid address
      pf = *(const float4*)(s + (size_t)((size_t)tn * 16 + srow) * 128 + sc4);
      if (tid < 320) {
        const float* rp = r + ((size_t)tn * 16 + (tid & 15)) * 3;
        rx = rp[0]; ry = rp[1]; rz = rp[2];
      }
    }
    BAR();   // sync2: hA visible

    // ---- Wfilt = rbf@Wr (K=32, split, 9 MFMA) ----
    f32x4 wacc[3], pacc[3];
    {
      const bf16x8 rh = *(const bf16x8*)&rbfh[p][l15][q4 * 8];
      const bf16x8 rl = *(const bf16x8*)&rbfl[p][l15][q4 * 8];
#pragma unroll
      for (int fci = 0; fci < 3; ++fci) {
        f32x4 a = __builtin_amdgcn_mfma_f32_16x16x32_bf16(rh, wrfh[fci], zero4, 0, 0, 0);
        a = __builtin_amdgcn_mfma_f32_16x16x32_bf16(rl, wrfh[fci], a, 0, 0, 0);
        a = __builtin_amdgcn_mfma_f32_16x16x32_bf16(rh, wrfl[fci], a, 0, 0, 0);
        wacc[fci] = a;
        pacc[fci] = zero4;
      }
    }
    // ---- GEMM2: phi = h@W2 (split, 36 MFMA) ----
#pragma unroll
    for (int ks = 0; ks < 4; ++ks) {
      const bf16x8 ah = *(const bf16x8*)&hAh[l15][ks * 32 + q4 * 8];
      const bf16x8 al = *(const bf16x8*)&hAl[l15][ks * 32 + q4 * 8];
#pragma unroll
      for (int fci = 0; fci < 3; ++fci) {
        pacc[fci] = __builtin_amdgcn_mfma_f32_16x16x32_bf16(ah, w2fh[fci][ks], pacc[fci], 0, 0, 0);
        pacc[fci] = __builtin_amdgcn_mfma_f32_16x16x32_bf16(al, w2fh[fci][ks], pacc[fci], 0, 0, 0);
        pacc[fci] = __builtin_amdgcn_mfma_f32_16x16x32_bf16(ah, w2fl[fci][ks], pacc[fci], 0, 0, 0);
      }
    }

    // ---- epilogue: every wave does all three categories (balanced) ----
#pragma unroll
    for (int rr = 0; rr < 4; ++rr) {
      const float4 u4 = urA[p][q4 * 4 + rr];
      const float sp0 = u4.w * (wacc[0][rr] + brv[0]) * (pacc[0][rr] + b2v[0]);
      const float sp1 = u4.w * (wacc[1][rr] + brv[1]) * (pacc[1][rr] + b2v[1]);
      const float sp2 = u4.w * (wacc[2][rr] + brv[2]) * (pacc[2][rr] + b2v[2]);
      accV1[0] += sp0 * vp[rr][0];
      accV1[1] += sp0 * vp[rr][1];
      accV1[2] += sp0 * vp[rr][2];
      accS += sp1;
      accV2[0] += sp2 * u4.x;
      accV2[1] += sp2 * u4.y;
      accV2[2] += sp2 * u4.z;
    }
    // no 3rd barrier: urA/rbf double-buffered; sA/hA hazards covered by
    // sync1/sync2 of adjacent iterations (audited: all RAW/WAR separated).
  }

  // ---- cross-lane reduce (sum q4 groups) + per-block partials ----
  float* pb = partials + (size_t)blockIdx.x * PART_STRIDE;
#pragma unroll
  for (int c = 0; c < 3; ++c) {
    float tv = accV1[c];
    tv += __shfl_xor(tv, 16);
    tv += __shfl_xor(tv, 32);
    if (ln < 16) pb[c * 128 + jcol] = tv;
  }
  {
    float tv = accS;
    tv += __shfl_xor(tv, 16);
    tv += __shfl_xor(tv, 32);
    if (ln < 16) pb[768 + jcol] = tv;
  }
#pragma unroll
  for (int c = 0; c < 3; ++c) {
    float tv = accV2[c];
    tv += __shfl_xor(tv, 16);
    tv += __shfl_xor(tv, 32);
    if (ln < 16) pb[384 + c * 128 + jcol] = tv;
  }
}

// --- kernel 3: reduce partials -> d_out. out[0:384]=out_v (3x128), [384:512]=out_s
__global__ void reduce_kernel(const float* __restrict__ partials, float* __restrict__ out) {
  const int o = blockIdx.x * 256 + threadIdx.x;   // 0..511
  float a0 = 0.f, a1 = 0.f, a2 = 0.f, a3 = 0.f;
  if (o < 384) {
#pragma unroll 4
    for (int b = 0; b < NBLK; b += 4) {
      a0 += partials[(size_t)(b + 0) * PART_STRIDE + o] + partials[(size_t)(b + 0) * PART_STRIDE + 384 + o];
      a1 += partials[(size_t)(b + 1) * PART_STRIDE + o] + partials[(size_t)(b + 1) * PART_STRIDE + 384 + o];
      a2 += partials[(size_t)(b + 2) * PART_STRIDE + o] + partials[(size_t)(b + 2) * PART_STRIDE + 384 + o];
      a3 += partials[(size_t)(b + 3) * PART_STRIDE + o] + partials[(size_t)(b + 3) * PART_STRIDE + 384 + o];
    }
    out[o] = (a0 + a1) + (a2 + a3);
  } else {
    const int j = o - 384;
#pragma unroll 4
    for (int b = 0; b < NBLK; b += 4) {
      a0 += partials[(size_t)(b + 0) * PART_STRIDE + 768 + j];
      a1 += partials[(size_t)(b + 1) * PART_STRIDE + 768 + j];
      a2 += partials[(size_t)(b + 2) * PART_STRIDE + 768 + j];
      a3 += partials[(size_t)(b + 3) * PART_STRIDE + 768 + j];
    }
    out[o] = (a0 + a1) + (a2 + a3);
  }
}

extern "C" void kernel_launch(void* const* d_in, const int* in_sizes, int n_in,
                              void* d_out, int out_size, void* d_ws, size_t ws_size,
                              hipStream_t stream) {
  const float* s  = (const float*)d_in[0];
  const float* r  = (const float*)d_in[1];
  const float* v  = (const float*)d_in[2];
  const float* W1 = (const float*)d_in[3];
  const float* b1 = (const float*)d_in[4];
  const float* W2 = (const float*)d_in[5];
  const float* b2 = (const float*)d_in[6];
  const float* Wr = (const float*)d_in[7];
  const float* br = (const float*)d_in[8];
  float* out = (float*)d_out;

  // ws: [partials 512*896 f32 = 1835008B][w1t hi+lo 65536B][w2t hi+lo 196608B][wrt hi+lo 49152B]
  char* ws = (char*)d_ws;
  float* partials = (float*)ws;
  unsigned short* w1t = (unsigned short*)(ws + (size_t)NBLK * PART_STRIDE * 4);
  unsigned short* w2t = w1t + 32768;
  unsigned short* wrt = w2t + 98304;

  prep_kernel<<<304, 256, 0, stream>>>(W1, W2, Wr, w1t, w2t, wrt);
  painn_main<<<NBLK, 512, 0, stream>>>(s, r, v, b1, b2, br, w1t, w2t, wrt, partials);
  reduce_kernel<<<2, 256, 0, stream>>>(partials, out);
}

// Round 10
// 727.956 us; speedup vs baseline: 1.7109x; 1.7109x over previous
//
#include <hip/hip_runtime.h>

// ---------------------------------------------------------------------------
// PaiNN edge message kernel, MI355X (gfx950)
// E=262144, F=128. Split-bf16 (hi/lo) MFMA GEMMs, fp32 elsewhere.
// R6..R10: revert launch_bounds (512,4)->(512,2). R5 showed (512,4) forces
// VGPR=64 -> 151MB scratch WRITE + 2.5GB FETCH (spill storm). R3 showed
// (512,2) gives VGPR=128, zero spills, weights remat'd from L2 (HBM-free).
// Keep R5's NBLK=512 grid (2 blocks/CU resident), balanced fc mapping
// {w, w+8, w+16}, v-prefetch at tile top, 2 lgkmcnt-only barriers/tile.
// ---------------------------------------------------------------------------

#define E_TOT  262144
#define NTILES 16384     // E / 16
#define NBLK   512       // 2 blocks/CU; 32 tiles per block
#define PART_STRIDE 896  // per-block partials: v1[3][128] v2[3][128] s[128]

typedef __attribute__((ext_vector_type(8))) short bf16x8;
typedef __attribute__((ext_vector_type(4))) float f32x4;
typedef __attribute__((ext_vector_type(4))) unsigned short u16x4;

static __device__ __forceinline__ unsigned short f2bf(float f) {
  union { float f; unsigned u; } x; x.f = f;
  unsigned r = x.u + 0x7fffu + ((x.u >> 16) & 1u);   // RNE
  return (unsigned short)(r >> 16);
}
static __device__ __forceinline__ float bf2f(unsigned short h) {
  union { unsigned u; float f; } x; x.u = ((unsigned)h) << 16;
  return x.f;
}

// lgkmcnt-only barrier (m201 pattern): LDS-correct, global loads stay in
// flight across it (no vmcnt(0) drain).
#define BAR() do {                                           \
    asm volatile("s_waitcnt lgkmcnt(0)" ::: "memory");       \
    __builtin_amdgcn_s_barrier();                            \
    asm volatile("" ::: "memory");                           \
  } while (0)

// --- kernel 1: weights -> bf16 hi/lo pairs, transposed for B-fragments ----
__global__ void prep_kernel(const float* __restrict__ W1, const float* __restrict__ W2,
                            const float* __restrict__ Wr,
                            unsigned short* __restrict__ w1t, unsigned short* __restrict__ w2t,
                            unsigned short* __restrict__ wrt) {
  int idx = blockIdx.x * 256 + threadIdx.x;
  if (idx < 16384) {                       // W1 (128x128) -> W1T[col][k]
    int k = idx >> 7, c = idx & 127;
    float x = W1[idx];
    unsigned short hi = f2bf(x);
    w1t[c * 128 + k] = hi;
    w1t[16384 + c * 128 + k] = f2bf(x - bf2f(hi));
  } else if (idx < 65536) {                // W2 (128x384) -> W2T[col][k]
    int i = idx - 16384;
    int k = i / 384, c = i % 384;
    float x = W2[i];
    unsigned short hi = f2bf(x);
    w2t[c * 128 + k] = hi;
    w2t[49152 + c * 128 + k] = f2bf(x - bf2f(hi));
  } else if (idx < 77824) {                // Wr (20x384) -> WrT[col][n], n padded to 32
    int i = idx - 65536;
    int c = i >> 5, n = i & 31;
    float x = (n < 20) ? Wr[n * 384 + c] : 0.0f;
    unsigned short hi = f2bf(x);
    wrt[c * 32 + n] = hi;
    wrt[12288 + c * 32 + n] = f2bf(x - bf2f(hi));
  }
}

// --- kernel 2: main. 512 threads = 8 waves. Tile = 16 edges. --------------
__global__ __launch_bounds__(512, 2) void painn_main(
    const float* __restrict__ s, const float* __restrict__ r, const float* __restrict__ v,
    const float* __restrict__ b1, const float* __restrict__ b2, const float* __restrict__ br,
    const unsigned short* __restrict__ w1t, const unsigned short* __restrict__ w2t,
    const unsigned short* __restrict__ wrt, float* __restrict__ partials)
{
  __shared__ __align__(16) unsigned short sAh[16][136], sAl[16][136];
  __shared__ __align__(16) unsigned short hAh[16][136], hAl[16][136];
  __shared__ __align__(16) unsigned short rbfh[2][16][40], rbfl[2][16][40];
  __shared__ float4 urA[2][16];   // dbuf: {ux, uy, uz, fcut}

  const int tid = threadIdx.x;
  const int wv  = tid >> 6;
  const int ln  = tid & 63;
  const int l15 = ln & 15;
  const int q4  = ln >> 4;
  const int jcol = wv * 16 + l15;          // per-wave column slot, 0..127

  // zero rbf pad cols 20..31 (read by K=32 MFMA) for both buffers, hi+lo
  for (int i = tid; i < 2 * 16 * 12; i += 512) {
    const int b = i / 192, rw = (i / 12) % 16, cc = 20 + (i % 12);
    rbfh[b][rw][cc] = 0; rbfl[b][rw][cc] = 0;
  }

  // ---- weight fragments (hi/lo); allocator remats overflow from L2 ----
  bf16x8 w1fh[4], w1fl[4];
#pragma unroll
  for (int ks = 0; ks < 4; ++ks) {
    w1fh[ks] = *(const bf16x8*)(w1t + jcol * 128 + ks * 32 + q4 * 8);
    w1fl[ks] = *(const bf16x8*)(w1t + 16384 + jcol * 128 + ks * 32 + q4 * 8);
  }
  const float b1v = b1[jcol];

  float b2v[3], brv[3];
  bf16x8 w2fh[3][4], w2fl[3][4], wrfh[3], wrfl[3];
#pragma unroll
  for (int fci = 0; fci < 3; ++fci) {
    const int j = jcol + fci * 128;        // fc = wv + 8*fci, j = fc*16+l15
    b2v[fci] = b2[j];
    brv[fci] = br[j];
#pragma unroll
    for (int ks = 0; ks < 4; ++ks) {
      w2fh[fci][ks] = *(const bf16x8*)(w2t + j * 128 + ks * 32 + q4 * 8);
      w2fl[fci][ks] = *(const bf16x8*)(w2t + 49152 + j * 128 + ks * 32 + q4 * 8);
    }
    wrfh[fci] = *(const bf16x8*)(wrt + j * 32 + q4 * 8);
    wrfl[fci] = *(const bf16x8*)(wrt + 12288 + j * 32 + q4 * 8);
  }

  float accS = 0.f;
  float accV1[3] = {0.f, 0.f, 0.f};
  float accV2[3] = {0.f, 0.f, 0.f};
  const f32x4 zero4 = {0.f, 0.f, 0.f, 0.f};

  // ---- prefetch s (one float4/thread) + r (threads<320, own edge copy) ----
  const int srow = tid >> 5;               // 0..15
  const int sc4  = (tid & 31) * 4;         // float col 0..124
  float4 pf = *(const float4*)(s + (size_t)((size_t)blockIdx.x * 16 + srow) * 128 + sc4);
  float rx = 0.f, ry = 0.f, rz = 0.f;
  if (tid < 320) {
    const float* rp = r + ((size_t)blockIdx.x * 16 + (tid & 15)) * 3;
    rx = rp[0]; ry = rp[1]; rz = rp[2];
  }

  int p = 0;
  for (int t = blockIdx.x; t < NTILES; t += NBLK, p ^= 1) {
    const int e0 = t * 16;

    // ---- v-prefetch for THIS tile (consumed in epilogue, ~2 phases later)
    float vp[4][3];
    {
      const float* vb = v + (size_t)e0 * 384 + jcol;
#pragma unroll
      for (int rr = 0; rr < 4; ++rr) {
        const int el = q4 * 4 + rr;
#pragma unroll
        for (int c = 0; c < 3; ++c)
          vp[rr][c] = vb[(size_t)el * 384 + c * 128];
      }
    }

    // ---- phase A: stage s tile (hi/lo), geometry + rbf from local r ----
    {
      u16x4 vh, vl;
      unsigned short h0 = f2bf(pf.x); vh[0] = h0; vl[0] = f2bf(pf.x - bf2f(h0));
      unsigned short h1 = f2bf(pf.y); vh[1] = h1; vl[1] = f2bf(pf.y - bf2f(h1));
      unsigned short h2 = f2bf(pf.z); vh[2] = h2; vl[2] = f2bf(pf.z - bf2f(h2));
      unsigned short h3 = f2bf(pf.w); vh[3] = h3; vl[3] = f2bf(pf.w - bf2f(h3));
      *(u16x4*)&sAh[srow][sc4] = vh;
      *(u16x4*)&sAl[srow][sc4] = vl;
    }
    if (tid < 320) {
      const float d = sqrtf(rx * rx + ry * ry + rz * rz);
      const float inv = 1.0f / d;
      const int n = tid >> 4;              // 0..19
      const float val = sinf(0.62831853071795864f * (float)(n + 1) * d) * inv;
      const unsigned short hi = f2bf(val);
      rbfh[p][tid & 15][n] = hi;
      rbfl[p][tid & 15][n] = f2bf(val - bf2f(hi));
      if (tid < 16) {
        const float fcut = (d < 5.0f) ? 0.5f * (cosf(0.62831853071795864f * d) + 1.0f) : 0.0f;
        float4 u4; u4.x = rx * inv; u4.y = ry * inv; u4.z = rz * inv; u4.w = fcut;
        urA[p][tid] = u4;
      }
    }
    BAR();   // sync1: sA visible

    // ---- GEMM1: h_pre = s@W1 (split, 12 MFMA) ----
    f32x4 hacc = zero4;
#pragma unroll
    for (int ks = 0; ks < 4; ++ks) {
      const bf16x8 ah = *(const bf16x8*)&sAh[l15][ks * 32 + q4 * 8];
      const bf16x8 al = *(const bf16x8*)&sAl[l15][ks * 32 + q4 * 8];
      hacc = __builtin_amdgcn_mfma_f32_16x16x32_bf16(ah, w1fh[ks], hacc, 0, 0, 0);
      hacc = __builtin_amdgcn_mfma_f32_16x16x32_bf16(al, w1fh[ks], hacc, 0, 0, 0);
      hacc = __builtin_amdgcn_mfma_f32_16x16x32_bf16(ah, w1fl[ks], hacc, 0, 0, 0);
    }
    // silu fp32, split-store h (D layout: row=q4*4+rr, col=jcol)
#pragma unroll
    for (int rr = 0; rr < 4; ++rr) {
      const float x = hacc[rr] + b1v;
      const float hvv = x / (1.0f + __expf(-x));
      const unsigned short hi = f2bf(hvv);
      hAh[q4 * 4 + rr][jcol] = hi;
      hAl[q4 * 4 + rr][jcol] = f2bf(hvv - bf2f(hi));
    }

    // ---- s/r prefetch for tile t+NBLK (stays in flight across barriers) ----
    {
      int tn = t + NBLK;
      if (tn >= NTILES) tn = blockIdx.x;   // harmless valid address
      pf = *(const float4*)(s + (size_t)((size_t)tn * 16 + srow) * 128 + sc4);
      if (tid < 320) {
        const float* rp = r + ((size_t)tn * 16 + (tid & 15)) * 3;
        rx = rp[0]; ry = rp[1]; rz = rp[2];
      }
    }
    BAR();   // sync2: hA visible

    // ---- Wfilt = rbf@Wr (K=32, split, 9 MFMA) ----
    f32x4 wacc[3], pacc[3];
    {
      const bf16x8 rh = *(const bf16x8*)&rbfh[p][l15][q4 * 8];
      const bf16x8 rl = *(const bf16x8*)&rbfl[p][l15][q4 * 8];
#pragma unroll
      for (int fci = 0; fci < 3; ++fci) {
        f32x4 a = __builtin_amdgcn_mfma_f32_16x16x32_bf16(rh, wrfh[fci], zero4, 0, 0, 0);
        a = __builtin_amdgcn_mfma_f32_16x16x32_bf16(rl, wrfh[fci], a, 0, 0, 0);
        a = __builtin_amdgcn_mfma_f32_16x16x32_bf16(rh, wrfl[fci], a, 0, 0, 0);
        wacc[fci] = a;
        pacc[fci] = zero4;
      }
    }
    // ---- GEMM2: phi = h@W2 (split, 36 MFMA) ----
#pragma unroll
    for (int ks = 0; ks < 4; ++ks) {
      const bf16x8 ah = *(const bf16x8*)&hAh[l15][ks * 32 + q4 * 8];
      const bf16x8 al = *(const bf16x8*)&hAl[l15][ks * 32 + q4 * 8];
#pragma unroll
      for (int fci = 0; fci < 3; ++fci) {
        pacc[fci] = __builtin_amdgcn_mfma_f32_16x16x32_bf16(ah, w2fh[fci][ks], pacc[fci], 0, 0, 0);
        pacc[fci] = __builtin_amdgcn_mfma_f32_16x16x32_bf16(al, w2fh[fci][ks], pacc[fci], 0, 0, 0);
        pacc[fci] = __builtin_amdgcn_mfma_f32_16x16x32_bf16(ah, w2fl[fci][ks], pacc[fci], 0, 0, 0);
      }
    }

    // ---- epilogue: every wave does all three categories (balanced) ----
#pragma unroll
    for (int rr = 0; rr < 4; ++rr) {
      const float4 u4 = urA[p][q4 * 4 + rr];
      const float sp0 = u4.w * (wacc[0][rr] + brv[0]) * (pacc[0][rr] + b2v[0]);
      const float sp1 = u4.w * (wacc[1][rr] + brv[1]) * (pacc[1][rr] + b2v[1]);
      const float sp2 = u4.w * (wacc[2][rr] + brv[2]) * (pacc[2][rr] + b2v[2]);
      accV1[0] += sp0 * vp[rr][0];
      accV1[1] += sp0 * vp[rr][1];
      accV1[2] += sp0 * vp[rr][2];
      accS += sp1;
      accV2[0] += sp2 * u4.x;
      accV2[1] += sp2 * u4.y;
      accV2[2] += sp2 * u4.z;
    }
    // no 3rd barrier: urA/rbf double-buffered; sA/hA hazards covered by
    // sync1/sync2 of adjacent iterations (audited: all RAW/WAR separated).
  }

  // ---- cross-lane reduce (sum q4 groups) + per-block partials ----
  float* pb = partials + (size_t)blockIdx.x * PART_STRIDE;
#pragma unroll
  for (int c = 0; c < 3; ++c) {
    float tv = accV1[c];
    tv += __shfl_xor(tv, 16);
    tv += __shfl_xor(tv, 32);
    if (ln < 16) pb[c * 128 + jcol] = tv;
  }
  {
    float tv = accS;
    tv += __shfl_xor(tv, 16);
    tv += __shfl_xor(tv, 32);
    if (ln < 16) pb[768 + jcol] = tv;
  }
#pragma unroll
  for (int c = 0; c < 3; ++c) {
    float tv = accV2[c];
    tv += __shfl_xor(tv, 16);
    tv += __shfl_xor(tv, 32);
    if (ln < 16) pb[384 + c * 128 + jcol] = tv;
  }
}

// --- kernel 3: reduce partials -> d_out. out[0:384]=out_v (3x128), [384:512]=out_s
__global__ void reduce_kernel(const float* __restrict__ partials, float* __restrict__ out) {
  const int o = blockIdx.x * 256 + threadIdx.x;   // 0..511
  float a0 = 0.f, a1 = 0.f, a2 = 0.f, a3 = 0.f;
  if (o < 384) {
#pragma unroll 4
    for (int b = 0; b < NBLK; b += 4) {
      a0 += partials[(size_t)(b + 0) * PART_STRIDE + o] + partials[(size_t)(b + 0) * PART_STRIDE + 384 + o];
      a1 += partials[(size_t)(b + 1) * PART_STRIDE + o] + partials[(size_t)(b + 1) * PART_STRIDE + 384 + o];
      a2 += partials[(size_t)(b + 2) * PART_STRIDE + o] + partials[(size_t)(b + 2) * PART_STRIDE + 384 + o];
      a3 += partials[(size_t)(b + 3) * PART_STRIDE + o] + partials[(size_t)(b + 3) * PART_STRIDE + 384 + o];
    }
    out[o] = (a0 + a1) + (a2 + a3);
  } else {
    const int j = o - 384;
#pragma unroll 4
    for (int b = 0; b < NBLK; b += 4) {
      a0 += partials[(size_t)(b + 0) * PART_STRIDE + 768 + j];
      a1 += partials[(size_t)(b + 1) * PART_STRIDE + 768 + j];
      a2 += partials[(size_t)(b + 2) * PART_STRIDE + 768 + j];
      a3 += partials[(size_t)(b + 3) * PART_STRIDE + 768 + j];
    }
    out[o] = (a0 + a1) + (a2 + a3);
  }
}

extern "C" void kernel_launch(void* const* d_in, const int* in_sizes, int n_in,
                              void* d_out, int out_size, void* d_ws, size_t ws_size,
                              hipStream_t stream) {
  const float* s  = (const float*)d_in[0];
  const float* r  = (const float*)d_in[1];
  const float* v  = (const float*)d_in[2];
  const float* W1 = (const float*)d_in[3];
  const float* b1 = (const float*)d_in[4];
  const float* W2 = (const float*)d_in[5];
  const float* b2 = (const float*)d_in[6];
  const float* Wr = (const float*)d_in[7];
  const float* br = (const float*)d_in[8];
  float* out = (float*)d_out;

  // ws: [partials 512*896 f32 = 1835008B][w1t hi+lo 65536B][w2t hi+lo 196608B][wrt hi+lo 49152B]
  char* ws = (char*)d_ws;
  float* partials = (float*)ws;
  unsigned short* w1t = (unsigned short*)(ws + (size_t)NBLK * PART_STRIDE * 4);
  unsigned short* w2t = w1t + 32768;
  unsigned short* wrt = w2t + 98304;

  prep_kernel<<<304, 256, 0, stream>>>(W1, W2, Wr, w1t, w2t, wrt);
  painn_main<<<NBLK, 512, 0, stream>>>(s, r, v, b1, b2, br, w1t, w2t, wrt, partials);
  reduce_kernel<<<2, 256, 0, stream>>>(partials, out);
}